// Round 3
// baseline (53056.921 us; speedup 1.0000x reference)
//
#include <hip/hip_runtime.h>

// ============================================================================
// Fused seq2seq GRU encoder/decoder + attention, fp32, MI355X (gfx950).
// Round 3 = round-2 kernel resubmitted verbatim (round 2 never ran:
// GPUAcquisitionTimeout). Occupancy-first reshape of the round-1 kernel.
//
// Round-1 evidence: VALUBusy 17.4%, Occupancy 12.26%, VGPR 256, LDS 147KB
//   -> 1 wave/SIMD, pure latency-bound. Fix = 4 waves/SIMD:
//  - ROWS=32 rows/block, 512 threads (8 waves), grid = 512 blocks (2/CU).
//  - Gate-triples n = 8m+wv split mod-8 across the 8 waves (13 for wv<4,
//    12 for wv>=4). K split across half-waves (kh = lane>>5), reduced with
//    __shfl_xor(.,32): no partial-sum LDS buffers.
//  - Gates processed in batches of 7+6 -> peak acc liveness ~42+13 regs.
//    __launch_bounds__(512,4) caps VGPR at 128 -> 2 blocks/CU resident.
//  - LDS 73.4KB/block (<80KB) -> 2 blocks/CU -> 16 waves/CU = 4/SIMD.
//  - attn_b dropped: scores only enter a softmax over t, and h1.attn_b is
//    t-independent -> softmax shift-invariance makes it a no-op.
//  - Weights read with wave-uniform indices -> scalar s_load broadcast.
//    enc stored transposed in ws: enc_t[t][d][row] (78.6MB), same-block
//    producer/consumer, coalesced over rows.
// ============================================================================

#define BB    16384
#define HH    100
#define TE    12
#define TDN   50
#define ROWS  32
#define NT    512
#define XS    101    // LDS stride for [ROWS][100] buffers (odd -> 2-way max)
#define GS    205    // LDS stride for xb [ROWS][200]
#define ENCT_OFF 16384

struct Params {
  const float *q, *p;
  const float *eWih0,*eWhh0,*ebih0,*ebhh0,*eWih1,*eWhh1,*ebih1,*ebhh1;
  const float *dWih0,*dWhh0,*dbih0,*dbhh0,*dWih1,*dWhh1,*dbih1,*dbhh1;
  const float *outW,*outb,*f1W,*f1b,*f2W,*f2b,*f3W,*f3b,*f4W,*f4b;
  float *ws;
  float *out;
};

__global__ void prep_attn_t(const float* __restrict__ attn_W, float* __restrict__ ws) {
  int i = blockIdx.x * 256 + threadIdx.x;
  if (i < HH * HH) {
    int d = i / HH, e = i % HH;
    ws[d * HH + e] = attn_W[e * HH + d];   // attn_t[d][e] = attn_W[e][d]
  }
}

__device__ __forceinline__ float sigf(float x)   { return 1.0f / (1.0f + __expf(-x)); }
__device__ __forceinline__ float tanhf_(float x) { float e = __expf(2.0f * x); return 1.0f - 2.0f / (e + 1.0f); }

// One GRU cell for this wave's gate residue class (n = 8m+wv), K-half split
// across half-waves, shfl_xor(32) reduction. Results in hv[0..12] (guarded).
template<int KI>   // KI = ih input width (100 or 200); hh is always 100
__device__ __forceinline__ void gru_cell_g8(
    const float* __restrict__ Wih, const float* __restrict__ Whh,
    const float* __restrict__ bih, const float* __restrict__ bhh,
    const float* xrow, const float* hrow, int wv, int kh, float* hv)
{
  constexpr int KH = KI / 2;
  const float* xh   = xrow + kh * KH;
  const float* hsrc = hrow + kh * 50;
  #pragma unroll
  for (int b = 0; b < 2; ++b) {                 // gate batches: 7 then 6
    const int MC = b ? 6 : 7;
    float gi[21], gh[21];
    #pragma unroll
    for (int i = 0; i < 21; ++i) { gi[i] = 0.f; gh[i] = 0.f; }
    // ---- ih GEMM (this K-half) ----
    #pragma unroll 1
    for (int kc = 0; kc < KH; kc += 10) {
      float xr[10];
      #pragma unroll
      for (int i = 0; i < 10; ++i) xr[i] = xh[kc + i];
      #pragma unroll
      for (int mm = 0; mm < 7; ++mm) {
        if (mm < MC) {
          const int n = 8 * (7 * b + mm) + wv;
          if (b == 0 || mm < 5 || n < HH) {     // only (b=1,mm=5) needs guard
            #pragma unroll
            for (int g = 0; g < 3; ++g) {
              const float* wr = Wih + (size_t)(n + g * HH) * KI + kh * KH + kc;
              float a = gi[3 * mm + g];
              #pragma unroll
              for (int i = 0; i < 10; ++i) a = fmaf(wr[i], xr[i], a);
              gi[3 * mm + g] = a;
            }
          }
        }
      }
    }
    // ---- hh GEMM (K=100, half=50) ----
    #pragma unroll 1
    for (int kc = 0; kc < 50; kc += 10) {
      float xr[10];
      #pragma unroll
      for (int i = 0; i < 10; ++i) xr[i] = hsrc[kc + i];
      #pragma unroll
      for (int mm = 0; mm < 7; ++mm) {
        if (mm < MC) {
          const int n = 8 * (7 * b + mm) + wv;
          if (b == 0 || mm < 5 || n < HH) {
            #pragma unroll
            for (int g = 0; g < 3; ++g) {
              const float* wr = Whh + (size_t)(n + g * HH) * HH + kh * 50 + kc;
              float a = gh[3 * mm + g];
              #pragma unroll
              for (int i = 0; i < 10; ++i) a = fmaf(wr[i], xr[i], a);
              gh[3 * mm + g] = a;
            }
          }
        }
      }
    }
    // ---- K-half reduction across half-waves ----
    #pragma unroll
    for (int i = 0; i < 21; ++i) {
      gi[i] += __shfl_xor(gi[i], 32);
      gh[i] += __shfl_xor(gh[i], 32);
    }
    // ---- combine (both halves compute; only lane<32 will store later) ----
    #pragma unroll
    for (int mm = 0; mm < 7; ++mm) {
      if (mm < MC) {
        const int m = 7 * b + mm;
        const int n = 8 * m + wv;
        if (b == 0 || mm < 5 || n < HH) {
          float ir  = gi[3 * mm + 0] + bih[n];
          float iz  = gi[3 * mm + 1] + bih[n + HH];
          float in_ = gi[3 * mm + 2] + bih[n + 2 * HH];
          float hr  = gh[3 * mm + 0] + bhh[n];
          float hz  = gh[3 * mm + 1] + bhh[n + HH];
          float hn  = gh[3 * mm + 2] + bhh[n + 2 * HH];
          float r  = sigf(ir + hr);
          float z  = sigf(iz + hz);
          float ng = tanhf_(in_ + r * hn);
          hv[m] = (1.0f - z) * ng + z * hrow[n];
        }
      }
    }
  }
}

__global__ __launch_bounds__(NT, 4) void fused_kernel(Params pr) {
  __shared__ float h0s[ROWS][XS];   // 12.9 KB
  __shared__ float h1s[ROWS][XS];   // 12.9 KB
  __shared__ float xb [ROWS][GS];   // 26.2 KB  encoder q_t / decoder [p_t|ctx]
  __shared__ float gvb[ROWS][XS];   // 12.9 KB  gvec = h1 @ attn_W
  __shared__ float scb[ROWS][13];   //  1.7 KB  attention scores
  __shared__ float ob [ROWS][53];   //  6.8 KB  out_context
  // total 73.4 KB -> 2 blocks/CU

  const int tid  = threadIdx.x;
  const int lane = tid & 63;
  const int row  = lane & 31;
  const int kh   = lane >> 5;                               // K-half
  const int wv   = __builtin_amdgcn_readfirstlane(tid >> 6); // gate class
  const int r0   = blockIdx.x * ROWS;
  const int grow = r0 + row;

  for (int it = tid; it < ROWS * XS; it += NT) {
    (&h0s[0][0])[it] = 0.f;
    (&h1s[0][0])[it] = 0.f;
  }
  __syncthreads();

  float hv[13];
  float*       encT  = pr.ws + ENCT_OFF;
  const float* attnT = pr.ws;

  // ===================== encoder: 12 steps =====================
  for (int t = 0; t < TE; ++t) {
    for (int it = tid; it < ROWS * HH; it += NT) {
      int r = it / HH, k = it % HH;
      xb[r][k] = pr.q[(size_t)(r0 + r) * (TE * HH) + t * HH + k];
    }
    __syncthreads();
    gru_cell_g8<100>(pr.eWih0, pr.eWhh0, pr.ebih0, pr.ebhh0,
                     &xb[row][0], &h0s[row][0], wv, kh, hv);
    __syncthreads();
    if (lane < 32) {
      #pragma unroll
      for (int m = 0; m < 13; ++m) { int n = 8 * m + wv; if (n < HH) h0s[row][n] = hv[m]; }
    }
    __syncthreads();
    gru_cell_g8<100>(pr.eWih1, pr.eWhh1, pr.ebih1, pr.ebhh1,
                     &h0s[row][0], &h1s[row][0], wv, kh, hv);
    __syncthreads();
    if (lane < 32) {
      float* ep = encT + (size_t)t * HH * BB;
      #pragma unroll
      for (int m = 0; m < 13; ++m) {
        int n = 8 * m + wv;
        if (n < HH) { h1s[row][n] = hv[m]; ep[(size_t)n * BB + grow] = hv[m]; }
      }
    }
    __syncthreads();
  }

  // ===================== decoder: 50 steps =====================
  for (int t = 0; t < TDN; ++t) {
    // A: gvec = h1 @ attn_W (gate dim d mod-8, K-half split)
    {
      float ga[13];
      #pragma unroll
      for (int m = 0; m < 13; ++m) ga[m] = 0.f;
      const float* hsrc = &h1s[row][0] + kh * 50;
      #pragma unroll 1
      for (int kc = 0; kc < 50; kc += 10) {
        float xr[10];
        #pragma unroll
        for (int i = 0; i < 10; ++i) xr[i] = hsrc[kc + i];
        #pragma unroll
        for (int m = 0; m < 13; ++m) {
          const int d = 8 * m + wv;
          if (m < 12 || d < HH) {
            const float* wr = attnT + (size_t)d * HH + kh * 50 + kc;
            float a = ga[m];
            #pragma unroll
            for (int i = 0; i < 10; ++i) a = fmaf(wr[i], xr[i], a);
            ga[m] = a;
          }
        }
      }
      #pragma unroll
      for (int m = 0; m < 13; ++m) ga[m] += __shfl_xor(ga[m], 32);
      if (lane < 32) {
        #pragma unroll
        for (int m = 0; m < 13; ++m) { int d = 8 * m + wv; if (d < HH) gvb[row][d] = ga[m]; }
      }
    }
    __syncthreads();

    // B: scores[t'] = gvec . enc[t']  (attn_b dropped: softmax shift-invariant)
    {
      const int ts = wv * 2 + kh;     // 16 slots, 12 active
      if (ts < TE) {
        float s = 0.f;
        const float* ep = encT + (size_t)ts * HH * BB + grow;
        #pragma unroll 1
        for (int kc = 0; kc < HH; kc += 10) {
          #pragma unroll
          for (int i = 0; i < 10; ++i)
            s = fmaf(gvb[row][kc + i], ep[(size_t)(kc + i) * BB], s);
        }
        scb[row][ts] = s;
      }
    }
    __syncthreads();

    // C: per-slot softmax (redundant, cheap) + ctx chunk -> xb[.][100+]
    {
      const int ds = wv * 2 + kh;                       // 16 slots over 100 dims
      const int d0 = ds < 4 ? ds * 7 : 28 + (ds - 4) * 6;
      const int dc = ds < 4 ? 7 : 6;
      float aw[TE]; float mx = -1e30f;
      #pragma unroll
      for (int k = 0; k < TE; ++k) { float v = scb[row][k]; aw[k] = v; mx = fmaxf(mx, v); }
      float ssum = 0.f;
      #pragma unroll
      for (int k = 0; k < TE; ++k) { float e = __expf(aw[k] - mx); aw[k] = e; ssum += e; }
      const float inv = 1.0f / ssum;
      float cx[7];
      #pragma unroll
      for (int i = 0; i < 7; ++i) cx[i] = 0.f;
      #pragma unroll
      for (int k = 0; k < TE; ++k) {
        const float* ep = encT + (size_t)(k * HH + d0) * BB + grow;
        const float a = aw[k];
        #pragma unroll
        for (int i = 0; i < 7; ++i) if (i < dc) cx[i] = fmaf(a, ep[(size_t)i * BB], cx[i]);
      }
      #pragma unroll
      for (int i = 0; i < 7; ++i) if (i < dc) xb[row][HH + d0 + i] = cx[i] * inv;
    }
    // D: stage p[:, t, :] -> xb[.][0..99] (disjoint columns vs C)
    for (int it = tid; it < ROWS * HH; it += NT) {
      int r = it / HH, k = it % HH;
      xb[r][k] = pr.p[(size_t)(r0 + r) * (TDN * HH) + t * HH + k];
    }
    __syncthreads();

    // E: GRU layer 0 (K=200)
    gru_cell_g8<200>(pr.dWih0, pr.dWhh0, pr.dbih0, pr.dbhh0,
                     &xb[row][0], &h0s[row][0], wv, kh, hv);
    __syncthreads();
    if (lane < 32) {
      #pragma unroll
      for (int m = 0; m < 13; ++m) { int n = 8 * m + wv; if (n < HH) h0s[row][n] = hv[m]; }
    }
    __syncthreads();

    // F: GRU layer 1
    gru_cell_g8<100>(pr.dWih1, pr.dWhh1, pr.dbih1, pr.dbhh1,
                     &h0s[row][0], &h1s[row][0], wv, kh, hv);
    __syncthreads();
    if (lane < 32) {
      #pragma unroll
      for (int m = 0; m < 13; ++m) { int n = 8 * m + wv; if (n < HH) h1s[row][n] = hv[m]; }
    }
    __syncthreads();
  }

  // ===================== out_context (last step only) =====================
  {
    float oa[7];
    #pragma unroll
    for (int i = 0; i < 7; ++i) oa[i] = 0.f;
    const int OC = (wv < 2) ? 7 : 6;            // 50 outputs = 2*7 + 6*6
    const float* xsrc = kh ? &xb[row][HH] : &h1s[row][0];   // [h1 | ctx] halves
    #pragma unroll 1
    for (int kc = 0; kc < HH; kc += 10) {
      float xr[10];
      #pragma unroll
      for (int i = 0; i < 10; ++i) xr[i] = xsrc[kc + i];
      #pragma unroll
      for (int mm = 0; mm < 7; ++mm) {
        if (mm < OC) {
          const int o = 8 * mm + wv;
          const float* wr = pr.outW + (size_t)o * (2 * HH) + kh * HH + kc;
          float a = oa[mm];
          #pragma unroll
          for (int i = 0; i < 10; ++i) a = fmaf(wr[i], xr[i], a);
          oa[mm] = a;
        }
      }
    }
    #pragma unroll
    for (int i = 0; i < 7; ++i) oa[i] += __shfl_xor(oa[i], 32);
    if (lane < 32) {
      #pragma unroll
      for (int mm = 0; mm < 7; ++mm) {
        if (mm < OC) { int o = 8 * mm + wv; ob[row][o] = fmaxf(oa[mm] + pr.outb[o], 0.f); }
      }
    }
  }
  __syncthreads();

  // ===================== final MLP + softmax (wave 0, lanes<32) ============
  if (wv == 0 && lane < 32) {
    float s1[25];
    #pragma unroll 1
    for (int o = 0; o < 25; ++o) {
      float a = pr.f1b[o];
      #pragma unroll
      for (int k = 0; k < 50; ++k) a = fmaf(pr.f1W[o * 50 + k], ob[row][k], a);
      s1[o] = fmaxf(a, 0.f);
    }
    float s2[10];
    #pragma unroll 1
    for (int o = 0; o < 10; ++o) {
      float a = pr.f2b[o];
      #pragma unroll
      for (int k = 0; k < 25; ++k) a = fmaf(pr.f2W[o * 25 + k], s1[k], a);
      s2[o] = fmaxf(a, 0.f);
    }
    float s3[4];
    #pragma unroll
    for (int o = 0; o < 4; ++o) {
      float a = pr.f3b[o];
      #pragma unroll
      for (int k = 0; k < 10; ++k) a = fmaf(pr.f3W[o * 10 + k], s2[k], a);
      s3[o] = fmaxf(a, 0.f);
    }
    float l0 = pr.f4b[0], l1 = pr.f4b[1];
    #pragma unroll
    for (int k = 0; k < 4; ++k) {
      l0 = fmaf(pr.f4W[k],     s3[k], l0);
      l1 = fmaf(pr.f4W[4 + k], s3[k], l1);
    }
    float mx = fmaxf(l0, l1);
    float e0 = __expf(l0 - mx), e1 = __expf(l1 - mx);
    float inv = 1.0f / (e0 + e1);
    pr.out[(size_t)grow * 2 + 0] = e0 * inv;
    pr.out[(size_t)grow * 2 + 1] = e1 * inv;
  }
}

extern "C" void kernel_launch(void* const* d_in, const int* in_sizes, int n_in,
                              void* d_out, int out_size, void* d_ws, size_t ws_size,
                              hipStream_t stream) {
  Params pr;
  pr.q      = (const float*)d_in[0];
  pr.p      = (const float*)d_in[1];
  // d_in[2] = attn_W (transposed by prep kernel into ws); d_in[3] = attn_b
  // (unused: softmax over t is invariant to the t-independent h1.attn_b term)
  pr.eWih0  = (const float*)d_in[4];
  pr.eWhh0  = (const float*)d_in[5];
  pr.ebih0  = (const float*)d_in[6];
  pr.ebhh0  = (const float*)d_in[7];
  pr.eWih1  = (const float*)d_in[8];
  pr.eWhh1  = (const float*)d_in[9];
  pr.ebih1  = (const float*)d_in[10];
  pr.ebhh1  = (const float*)d_in[11];
  pr.dWih0  = (const float*)d_in[12];
  pr.dWhh0  = (const float*)d_in[13];
  pr.dbih0  = (const float*)d_in[14];
  pr.dbhh0  = (const float*)d_in[15];
  pr.dWih1  = (const float*)d_in[16];
  pr.dWhh1  = (const float*)d_in[17];
  pr.dbih1  = (const float*)d_in[18];
  pr.dbhh1  = (const float*)d_in[19];
  pr.outW   = (const float*)d_in[20];
  pr.outb   = (const float*)d_in[21];
  pr.f1W    = (const float*)d_in[22];
  pr.f1b    = (const float*)d_in[23];
  pr.f2W    = (const float*)d_in[24];
  pr.f2b    = (const float*)d_in[25];
  pr.f3W    = (const float*)d_in[26];
  pr.f3b    = (const float*)d_in[27];
  pr.f4W    = (const float*)d_in[28];
  pr.f4b    = (const float*)d_in[29];
  pr.ws     = (float*)d_ws;
  pr.out    = (float*)d_out;

  prep_attn_t<<<40, 256, 0, stream>>>((const float*)d_in[2], (float*)d_ws);
  fused_kernel<<<BB / ROWS, NT, 0, stream>>>(pr);
}